// Round 1
// baseline (101.770 us; speedup 1.0000x reference)
//
#include <hip/hip_runtime.h>

// IDWT 2D Haar: out[b, 4c+o, 2h+i, 2w+j] = (sum_n x[b, n*C+c, h, w]) * filt[o,i,j]
// x: (B=8, 192, 128, 128) f32; filt: (4,2,2) f32; out: (8, 192, 256, 256) f32.

constexpr int B  = 8;
constexpr int C  = 48;    // groups
constexpr int C4 = 192;   // 4*C
constexpr int H  = 128;
constexpr int W  = 128;
constexpr int HO = 256;
constexpr int WO = 256;
constexpr int W2 = W / 2; // 2 w-positions per thread

__global__ __launch_bounds__(256)
void idwt2d_haar_kernel(const float* __restrict__ x,
                        const float* __restrict__ filt,
                        float* __restrict__ out) {
    // linear index over (b, c, h, w2); consecutive lanes -> consecutive w2
    unsigned idx = blockIdx.x * blockDim.x + threadIdx.x;
    const int w2 = idx & (W2 - 1);        // 64 per row
    unsigned t = idx >> 6;
    const int h = t & (H - 1);            // 128
    t >>= 7;
    const int c = t % C;
    const int b = t / C;
    if (b >= B) return;

    const int w = w2 * 2;
    const long long plane = (long long)H * W;

    // sum over 4 subbands: x[b, n*C + c, h, w..w+1]
    const float* xp = x + ((long long)b * C4 + c) * plane + (long long)h * W + w;
    float2 v0 = *(const float2*)(xp);
    float2 v1 = *(const float2*)(xp + (long long)C * plane);
    float2 v2 = *(const float2*)(xp + (long long)2 * C * plane);
    float2 v3 = *(const float2*)(xp + (long long)3 * C * plane);
    const float s0 = (v0.x + v1.x) + (v2.x + v3.x);
    const float s1 = (v0.y + v1.y) + (v2.y + v3.y);

    // out base: channel 4c, row 2h, col 2w  (2w == 4*w2, 16B aligned)
    float* op = out + (((long long)b * C4 + 4 * c) * HO + 2 * h) * (long long)WO + 2 * w;
    #pragma unroll
    for (int o = 0; o < 4; ++o) {
        #pragma unroll
        for (int i = 0; i < 2; ++i) {
            const float f0 = filt[o * 4 + i * 2 + 0];
            const float f1 = filt[o * 4 + i * 2 + 1];
            float4 v = make_float4(s0 * f0, s0 * f1, s1 * f0, s1 * f1);
            *(float4*)(op + ((long long)o * HO + i) * WO) = v;
        }
    }
}

extern "C" void kernel_launch(void* const* d_in, const int* in_sizes, int n_in,
                              void* d_out, int out_size, void* d_ws, size_t ws_size,
                              hipStream_t stream) {
    const float* x    = (const float*)d_in[0];
    const float* filt = (const float*)d_in[1];
    float* out = (float*)d_out;

    const long long total = (long long)B * C * H * W2; // 3,145,728 threads
    const int block = 256;
    const int grid = (int)((total + block - 1) / block); // 12288
    idwt2d_haar_kernel<<<grid, block, 0, stream>>>(x, filt, out);
}